// Round 1
// baseline (265.839 us; speedup 1.0000x reference)
//
#include <hip/hip_runtime.h>
#include <stdint.h>

#define DEV static __device__ __forceinline__

typedef __attribute__((ext_vector_type(8))) __bf16 bfx8;
typedef __attribute__((ext_vector_type(4))) float f32x4;

DEV short f2bfbits(float f) {
  union { float f; unsigned u; } v; v.f = f;
  unsigned r = v.u + 0x7fffu + ((v.u >> 16) & 1u);
  return (short)(r >> 16);
}

DEV void gload_lds16(const void* g, void* lds) {
  __builtin_amdgcn_global_load_lds(
      (const __attribute__((address_space(1))) void*)g,
      (__attribute__((address_space(3))) void*)lds, 16, 0, 0);
}

// ---------------- prep kernels ----------------

__global__ void k_cvt_x(const float* __restrict__ src, short* __restrict__ dst) {
  int i = blockIdx.x * 256 + threadIdx.x;            // 4 floats per thread
  float4 v = ((const float4*)src)[i];
  union { short s[4]; uint64_t u; } o;
  o.s[0] = f2bfbits(v.x); o.s[1] = f2bfbits(v.y);
  o.s[2] = f2bfbits(v.z); o.s[3] = f2bfbits(v.w);
  ((uint64_t*)dst)[i] = o.u;
}

// src [R][C] f32 -> dst [C][R] bf16
__global__ void k_transpose(const float* __restrict__ src, short* __restrict__ dst,
                            int R, int C) {
  __shared__ float tile[32][33];
  int c0 = blockIdx.x * 32, r0 = blockIdx.y * 32;
  int tx = threadIdx.x, ty = threadIdx.y;            // block (32,8)
  #pragma unroll
  for (int j = 0; j < 32; j += 8)
    tile[ty + j][tx] = src[(size_t)(r0 + ty + j) * C + c0 + tx];
  __syncthreads();
  #pragma unroll
  for (int j = 0; j < 32; j += 8)
    dst[(size_t)(c0 + ty + j) * R + r0 + tx] = f2bfbits(tile[tx][ty + j]);
}

// msk[b][n]: n==0 -> 1 else mask[b][n-1]
__global__ void k_mask(const int* __restrict__ mask, unsigned char* __restrict__ msk) {
  int i = blockIdx.x * 256 + threadIdx.x;            // [0, 4096)
  int b = i >> 10, n = i & 1023;
  msk[i] = (n == 0) ? (unsigned char)1 : (unsigned char)(mask[b * 1023 + n - 1] != 0);
}

// ---------------- GEMM: C = A[M][K] @ Bt[N][K]^T + bias ----------------
// mode 0: scatter to q/k/vT (bf16), N=3072.  mode 1: f32 out + bias, N=1024.
__global__ __launch_bounds__(256)
void k_gemm(const short* __restrict__ A, const short* __restrict__ Bt,
            const float* __restrict__ bias, int K, int mode,
            short* __restrict__ q, short* __restrict__ kk,
            short* __restrict__ vT, float* __restrict__ outF) {
  __shared__ short As[128 * 32];
  __shared__ short Bs[128 * 32];
  const int t = threadIdx.x;
  const int l = t & 63, w = t >> 6;
  const int lr = l & 15, lk = l >> 4;
  const int m0 = blockIdx.y * 128, n0 = blockIdx.x * 128;
  const int wr = (w >> 1) * 64, wc = (w & 1) * 64;
  f32x4 acc[4][4] = {};

  const int srow = t >> 2;
  const int sc8 = (t & 3) * 8;
  const size_t aoff1 = (size_t)(m0 + srow) * K + sc8;
  const size_t aoff2 = (size_t)(m0 + srow + 64) * K + sc8;
  const size_t boff1 = (size_t)(n0 + srow) * K + sc8;
  const size_t boff2 = (size_t)(n0 + srow + 64) * K + sc8;
  short* asd1 = As + (t & ~63) * 8;
  short* asd2 = As + (t & ~63) * 8 + 2048;
  short* bsd1 = Bs + (t & ~63) * 8;
  short* bsd2 = Bs + (t & ~63) * 8 + 2048;

  for (int k0 = 0; k0 < K; k0 += 32) {
    gload_lds16(A + aoff1 + k0, asd1);
    gload_lds16(A + aoff2 + k0, asd2);
    gload_lds16(Bt + boff1 + k0, bsd1);
    gload_lds16(Bt + boff2 + k0, bsd2);
    __syncthreads();
    bfx8 af[4], bf[4];
    #pragma unroll
    for (int m = 0; m < 4; m++)
      af[m] = *(const bfx8*)&As[(wr + m * 16 + lr) * 32 + lk * 8];
    #pragma unroll
    for (int n = 0; n < 4; n++)
      bf[n] = *(const bfx8*)&Bs[(wc + n * 16 + lr) * 32 + lk * 8];
    #pragma unroll
    for (int m = 0; m < 4; m++)
      #pragma unroll
      for (int n = 0; n < 4; n++)
        acc[m][n] = __builtin_amdgcn_mfma_f32_16x16x32_bf16(af[m], bf[n], acc[m][n], 0, 0, 0);
    __syncthreads();
  }

  if (mode == 0) {
    #pragma unroll
    for (int m = 0; m < 4; m++) {
      int grb = m0 + wr + m * 16 + 4 * lk;
      #pragma unroll
      for (int n = 0; n < 4; n++) {
        int gc = n0 + wc + n * 16 + lr;
        float bv = bias[gc];
        int which = gc >> 10, rem = gc & 1023;
        int hh = rem >> 6, dd = rem & 63;
        #pragma unroll
        for (int i = 0; i < 4; i++) {
          int gr = grb + i;
          int bb = gr >> 10, nn = gr & 1023;
          size_t bh = (size_t)(bb * 16 + hh);
          short val = f2bfbits(acc[m][n][i] + bv);
          if (which == 0)      q [(bh << 16) + ((size_t)nn << 6) + dd] = val;
          else if (which == 1) kk[(bh << 16) + ((size_t)nn << 6) + dd] = val;
          else                 vT[(bh << 16) + ((size_t)dd << 10) + nn] = val;
        }
      }
    }
  } else {
    #pragma unroll
    for (int m = 0; m < 4; m++) {
      #pragma unroll
      for (int n = 0; n < 4; n++) {
        int gc = n0 + wc + n * 16 + lr;
        float bv = bias[gc];
        #pragma unroll
        for (int i = 0; i < 4; i++) {
          int gr = m0 + wr + m * 16 + 4 * lk + i;
          outF[(size_t)gr * 1024 + gc] = acc[m][n][i] + bv;
        }
      }
    }
  }
}

// ---------------- fused attention ----------------
// One workgroup = one (b,h) x 16 query rows. LDS S[16][1024] f32, XOR-swizzled.
DEV int swz(int row, int c) {
  return row * 1024 + ((((c >> 2) ^ (row & 7)) << 2) | (c & 3));
}

__global__ __launch_bounds__(256)
void k_attn(const short* __restrict__ q, const short* __restrict__ kmat,
            const short* __restrict__ vT, const unsigned char* __restrict__ msk,
            float* __restrict__ attn, short* __restrict__ ctx) {
  __shared__ float S[16 * 1024];
  const int t = threadIdx.x, l = t & 63, w = t >> 6;
  const int lr = l & 15, lk = l >> 4;
  const int rt = blockIdx.x, h = blockIdx.y, b = blockIdx.z;
  const int bh = b * 16 + h;
  const int r0 = rt * 16;
  const size_t kvbase = (size_t)bh << 16;  // bh * 1024 * 64

  // ---- phase 1: S = mask(QK^T * scale) ----
  bfx8 aq0 = *(const bfx8*)&q[kvbase + ((size_t)(r0 + lr) << 6) + lk * 8];
  bfx8 aq1 = *(const bfx8*)&q[kvbase + ((size_t)(r0 + lr) << 6) + 32 + lk * 8];
  bool rowok[4];
  #pragma unroll
  for (int i = 0; i < 4; i++) rowok[i] = msk[b * 1024 + r0 + 4 * lk + i] != 0;
  const float NEG = -3.402823466e38f;

  for (int cf = 0; cf < 16; cf++) {
    int col0 = w * 256 + cf * 16;
    const short* kp = &kmat[kvbase + ((size_t)(col0 + lr) << 6) + lk * 8];
    bfx8 bk0 = *(const bfx8*)kp;
    bfx8 bk1 = *(const bfx8*)(kp + 32);
    f32x4 acc = {};
    acc = __builtin_amdgcn_mfma_f32_16x16x32_bf16(aq0, bk0, acc, 0, 0, 0);
    acc = __builtin_amdgcn_mfma_f32_16x16x32_bf16(aq1, bk1, acc, 0, 0, 0);
    bool colok = msk[b * 1024 + col0 + lr] != 0;
    int col = col0 + lr;
    #pragma unroll
    for (int i = 0; i < 4; i++) {
      int row = 4 * lk + i;
      S[swz(row, col)] = (colok && rowok[i]) ? acc[i] * 0.03125f : NEG;
    }
  }
  __syncthreads();

  // ---- phase 2: softmax per row (wave w owns rows 4w..4w+3), write attn ----
  for (int rr = 0; rr < 4; rr++) {
    int row = w * 4 + rr;
    float v[16];
    #pragma unroll
    for (int j = 0; j < 16; j++) v[j] = S[swz(row, l + j * 64)];
    float mx = v[0];
    #pragma unroll
    for (int j = 1; j < 16; j++) mx = fmaxf(mx, v[j]);
    #pragma unroll
    for (int off = 32; off > 0; off >>= 1) mx = fmaxf(mx, __shfl_xor(mx, off));
    float sum = 0.f;
    #pragma unroll
    for (int j = 0; j < 16; j++) { v[j] = __expf(v[j] - mx); sum += v[j]; }
    #pragma unroll
    for (int off = 32; off > 0; off >>= 1) sum += __shfl_xor(sum, off);
    float inv = 1.0f / sum;
    size_t obase = ((size_t)bh * 1024 + r0 + row) * 1024;
    #pragma unroll
    for (int j = 0; j < 16; j++) {
      float p = v[j] * inv;
      S[swz(row, l + j * 64)] = p;
      attn[obase + l + j * 64] = p;
    }
  }
  __syncthreads();

  // ---- phase 3: ctx = P @ V (wave w owns head-dims 16w..16w+15) ----
  const size_t vbase = kvbase;  // vT: [bh][64][1024]
  f32x4 oacc = {};
  for (int ks = 0; ks < 32; ks++) {
    bfx8 bv = *(const bfx8*)&vT[vbase + ((size_t)(w * 16 + lr) << 10) + ks * 32 + lk * 8];
    int cbase = ks * 32 + lk * 8;
    float4 f0 = *(const float4*)&S[swz(lr, cbase)];
    float4 f1 = *(const float4*)&S[swz(lr, cbase + 4)];
    bfx8 pa;
    pa[0] = (__bf16)f0.x; pa[1] = (__bf16)f0.y; pa[2] = (__bf16)f0.z; pa[3] = (__bf16)f0.w;
    pa[4] = (__bf16)f1.x; pa[5] = (__bf16)f1.y; pa[6] = (__bf16)f1.z; pa[7] = (__bf16)f1.w;
    oacc = __builtin_amdgcn_mfma_f32_16x16x32_bf16(pa, bv, oacc, 0, 0, 0);
  }
  #pragma unroll
  for (int i = 0; i < 4; i++)
    ctx[(((size_t)b << 10) + r0 + 4 * lk + i) * 1024 + (h << 6) + (w << 4) + lr] =
        f2bfbits(oacc[i]);
}

// ---------------- launch ----------------

extern "C" void kernel_launch(void* const* d_in, const int* in_sizes, int n_in,
                              void* d_out, int out_size, void* d_ws, size_t ws_size,
                              hipStream_t stream) {
  const float* x    = (const float*)d_in[0];
  const int*   mask = (const int*)d_in[1];
  const float* Wqkv = (const float*)d_in[2];
  const float* bqkv = (const float*)d_in[3];
  const float* Wout = (const float*)d_in[4];
  const float* bout = (const float*)d_in[5];
  float* out  = (float*)d_out;
  float* attn = out + (size_t)4 * 1024 * 1024;

  char* ws = (char*)d_ws;
  short* xb    = (short*)(ws);                  //  8 MB  x bf16 [4096][1024]
  short* wqkvT = (short*)(ws + 8388608);        //  6 MB  [3072][1024]
  short* woutT = (short*)(ws + 14680064);       //  2 MB  [1024][1024]
  short* qws   = (short*)(ws + 16777216);       //  8 MB  [64][1024][64]
  short* kws   = (short*)(ws + 25165824);       //  8 MB  [64][1024][64]
  short* vTws  = (short*)(ws + 33554432);       //  8 MB  [64][64][1024]
  short* ctx   = (short*)(ws + 41943040);       //  8 MB  [4096][1024]
  unsigned char* msk = (unsigned char*)(ws + 50331648);  // 4 KB

  k_cvt_x<<<4096, 256, 0, stream>>>(x, xb);
  k_transpose<<<dim3(96, 32), dim3(32, 8), 0, stream>>>(Wqkv, wqkvT, 1024, 3072);
  k_transpose<<<dim3(32, 32), dim3(32, 8), 0, stream>>>(Wout, woutT, 1024, 1024);
  k_mask<<<16, 256, 0, stream>>>(mask, msk);
  k_gemm<<<dim3(24, 32), 256, 0, stream>>>(xb, wqkvT, bqkv, 1024, 0,
                                           qws, kws, vTws, nullptr);
  k_attn<<<dim3(64, 16, 4), 256, 0, stream>>>(qws, kws, vTws, msk, attn, ctx);
  k_gemm<<<dim3(8, 32), 256, 0, stream>>>(ctx, woutT, bout, 1024, 1,
                                          nullptr, nullptr, nullptr, out);
}